// Round 1
// baseline (1204.715 us; speedup 1.0000x reference)
//
#include <hip/hip_runtime.h>

#define NSEG 512
#define NSPLIT 64

typedef __attribute__((ext_vector_type(8))) short short8;
typedef __attribute__((ext_vector_type(4))) float floatx4;

// ws layout (bytes)
#define WS_WBT   0            // short [256][256]  Wback^T (bf16)
#define WS_WAT   131072       // short [256][32]   WA^T (bf16)
#define WS_WBT2  147456       // short [256][64]   WB^T (bf16, K padded 48->64 with zeros)
#define WS_VPART 180224       // float [NSPLIT][NSEG] value partial sums
#define WS_CPART 311296       // float [NSPLIT][NSEG] count partial sums
// total 442368 bytes of d_ws used

__device__ __forceinline__ float bf2f(short s) {
  unsigned u = ((unsigned)(unsigned short)s) << 16;
  return __builtin_bit_cast(float, u);
}
__device__ __forceinline__ short f2bf(float f) {  // round-to-nearest-even
  unsigned u = __builtin_bit_cast(unsigned, f);
  u += 0x7FFFu + ((u >> 16) & 1u);
  return (short)(u >> 16);
}

__global__ void prep_kernel(const float* __restrict__ WA, const float* __restrict__ WB,
                            const float* __restrict__ Wback, char* __restrict__ ws) {
  short* wbT  = (short*)(ws + WS_WBT);
  short* waT  = (short*)(ws + WS_WAT);
  short* wbT2 = (short*)(ws + WS_WBT2);
  float* vz   = (float*)(ws + WS_VPART);
  int tid = blockIdx.x * blockDim.x + threadIdx.x;
  int stride = gridDim.x * blockDim.x;
  for (int i = tid; i < 256*256; i += stride) {      // Wback [k][n] -> wbT[n][k]
    int k = i >> 8, n = i & 255;
    wbT[n*256 + k] = f2bf(Wback[i]);
  }
  for (int i = tid; i < 32*256; i += stride) {       // WA [k][n] -> waT[n][k]
    int k = i >> 8, n = i & 255;
    waT[n*32 + k] = f2bf(WA[i]);
  }
  for (int i = tid; i < 256*64; i += stride) {       // WB [k][n] -> wbT2[n][k], pad K to 64
    int n = i >> 6, k = i & 63;
    wbT2[i] = (k < 48) ? f2bf(WB[k*256 + n]) : (short)0;
  }
  for (int i = tid; i < 2*NSPLIT*NSEG; i += stride) vz[i] = 0.0f;  // vpart+cpart contiguous
}

__global__ __launch_bounds__(256, 2) void fused_kernel(
    const float* __restrict__ featsA, const float* __restrict__ featsB,
    const float* __restrict__ mA, const float* __restrict__ sA,
    const float* __restrict__ mB, const float* __restrict__ sB,
    const float* __restrict__ bA, const float* __restrict__ gA, const float* __restrict__ betaA,
    const float* __restrict__ bB, const float* __restrict__ gB, const float* __restrict__ betaB,
    const float* __restrict__ bback, const float* __restrict__ Wv,
    const int* __restrict__ bidx,
    const char* __restrict__ ws, float* __restrict__ vpart, float* __restrict__ cpart,
    int tilesA, int nA, int nB)
{
  // LDS. ftile stride 72 (+8 pad), ztile stride 264 (+8 pad): 2-way-max bank aliasing on b128 reads.
  __shared__ __attribute__((aligned(16))) short ftile[64*72];    // 9216 B
  __shared__ __attribute__((aligned(16))) short ztile[64*264];   // 33792 B
  __shared__ float red1[64][4];
  __shared__ float red2[64][4];
  __shared__ float mu_s[64];
  __shared__ float rs_s[64];
  __shared__ float lng_s[256];
  __shared__ float lnb_s[256];
  __shared__ float vpw[4][64];

  const int tid  = threadIdx.x;
  const int wave = tid >> 6;
  const int lane = tid & 63;
  const int l15  = lane & 15;
  const int quad = lane >> 4;

  const bool isA = (blockIdx.x < (unsigned)tilesA);
  const int  tb  = isA ? blockIdx.x : (blockIdx.x - tilesA);
  const int  r0  = tb * 64;
  const int  nrows = isA ? nA : nB;
  const int  valid = min(64, nrows - r0);
  const float* feats = isA ? featsA : featsB;
  const float* mean  = isA ? mA : mB;
  const float* stdv  = isA ? sA : sB;
  const float* bias  = isA ? bA : bB;
  const float* lng   = isA ? gA : gB;
  const float* lnb   = isA ? betaA : betaB;
  const short* weT   = (const short*)(ws + (isA ? WS_WAT : WS_WBT2));
  const int kstride  = isA ? 32 : 64;
  const int ksteps   = isA ? 1 : 2;
  const short* wbT   = (const short*)(ws + WS_WBT);

  // ---- phase 0: zero ftile, stage LN params ----
  for (int i = tid; i < 64*72/2; i += 256) ((int*)ftile)[i] = 0;
  lng_s[tid] = lng[tid];
  lnb_s[tid] = lnb[tid];
  if (tid < 64) vpw[0][tid] = 0.0f;   // (unused slot init; real writes below)
  __syncthreads();

  // ---- phase 1: stage normalized+clipped feats as bf16 into ftile [64][K] ----
  {
    const int f = isA ? 32 : 48;
    const int tot = 64 * f;
    for (int e = tid; e < tot; e += 256) {
      int row, col;
      if (isA) { row = e >> 5; col = e & 31; }
      else     { row = e / 48; col = e - row * 48; }
      float x = 0.0f;
      if (row < valid) x = feats[(size_t)(r0 + row) * f + col];
      float h = (x - mean[col]) / stdv[col];
      h = fminf(fmaxf(h, -5.0f), 5.0f);
      ftile[row*72 + col] = f2bf(h);
    }
  }
  __syncthreads();

  // ---- phase 2: GEMM1  h[64][256] = ftile @ W_embed  (wave owns cols 64w..64w+63) ----
  short8 bf1[2][4];
  for (int kk = 0; kk < ksteps; kk++)
    #pragma unroll
    for (int nt = 0; nt < 4; nt++)
      bf1[kk][nt] = *(const short8*)(weT + (64*wave + 16*nt + l15) * kstride + kk*32 + quad*8);

  floatx4 acc1[4][4];
  #pragma unroll
  for (int mt = 0; mt < 4; mt++)
    #pragma unroll
    for (int nt = 0; nt < 4; nt++)
      acc1[mt][nt] = 0.0f;

  for (int kk = 0; kk < ksteps; kk++) {
    short8 af[4];
    #pragma unroll
    for (int mt = 0; mt < 4; mt++)
      af[mt] = *(const short8*)(ftile + (16*mt + l15)*72 + kk*32 + quad*8);
    #pragma unroll
    for (int mt = 0; mt < 4; mt++)
      #pragma unroll
      for (int nt = 0; nt < 4; nt++)
        acc1[mt][nt] = __builtin_amdgcn_mfma_f32_16x16x32_bf16(af[mt], bf1[kk][nt], acc1[mt][nt], 0, 0, 0);
  }

  // epilogue 1: bias + relu -> ztile (bf16). C-layout: col=l15(+16nt+64w), row=4*quad+r (+16mt)
  #pragma unroll
  for (int nt = 0; nt < 4; nt++) {
    int col = 64*wave + 16*nt + l15;
    float bb = bias[col];
    #pragma unroll
    for (int mt = 0; mt < 4; mt++)
      #pragma unroll
      for (int r = 0; r < 4; r++) {
        float h = fmaxf(acc1[mt][nt][r] + bb, 0.0f);
        ztile[(16*mt + 4*quad + r)*264 + col] = f2bf(h);
      }
  }
  __syncthreads();

  // ---- phase 3: LayerNorm over d=256, in-place on ztile. 4 threads/row x 64 cols ----
  {
    const int row = tid >> 2, part = tid & 3;
    short* zr = ztile + row*264 + part*64;
    float s = 0.0f, s2 = 0.0f;
    #pragma unroll
    for (int j8 = 0; j8 < 8; j8++) {
      short8 v8 = *(const short8*)(zr + j8*8);
      #pragma unroll
      for (int e = 0; e < 8; e++) { float v = bf2f(v8[e]); s += v; s2 += v*v; }
    }
    red1[row][part] = s;
    red2[row][part] = s2;
  }
  __syncthreads();
  if (tid < 64) {
    float s  = red1[tid][0] + red1[tid][1] + red1[tid][2] + red1[tid][3];
    float s2 = red2[tid][0] + red2[tid][1] + red2[tid][2] + red2[tid][3];
    float mu  = s * (1.0f/256.0f);
    float var = fmaxf(s2 * (1.0f/256.0f) - mu*mu, 0.0f);
    mu_s[tid] = mu;
    rs_s[tid] = rsqrtf(var + 1e-5f);
  }
  __syncthreads();
  {
    const int row = tid >> 2, part = tid & 3;
    short* zr = ztile + row*264 + part*64;
    const float mu = mu_s[row], rs = rs_s[row];
    #pragma unroll
    for (int j8 = 0; j8 < 8; j8++) {
      short8 v8 = *(const short8*)(zr + j8*8);
      short8 o8;
      #pragma unroll
      for (int e = 0; e < 8; e++) {
        int col = part*64 + j8*8 + e;
        float v = bf2f(v8[e]);
        v = (v - mu) * rs * lng_s[col] + lnb_s[col];
        o8[e] = f2bf(v);
      }
      *(short8*)(zr + j8*8) = o8;
    }
  }
  __syncthreads();

  // ---- phase 4: GEMM2  y = relu(z @ Wback + bback), K=256 in 8 steps ----
  floatx4 acc2[4][4];
  #pragma unroll
  for (int mt = 0; mt < 4; mt++)
    #pragma unroll
    for (int nt = 0; nt < 4; nt++)
      acc2[mt][nt] = 0.0f;

  for (int kk = 0; kk < 8; kk++) {
    short8 bf[4];
    #pragma unroll
    for (int nt = 0; nt < 4; nt++)
      bf[nt] = *(const short8*)(wbT + (64*wave + 16*nt + l15)*256 + kk*32 + quad*8);
    short8 af[4];
    #pragma unroll
    for (int mt = 0; mt < 4; mt++)
      af[mt] = *(const short8*)(ztile + (16*mt + l15)*264 + kk*32 + quad*8);
    #pragma unroll
    for (int mt = 0; mt < 4; mt++)
      #pragma unroll
      for (int nt = 0; nt < 4; nt++)
        acc2[mt][nt] = __builtin_amdgcn_mfma_f32_16x16x32_bf16(af[mt], bf[nt], acc2[mt][nt], 0, 0, 0);
  }

  // ---- phase 5: v = relu(y)·Wv per row; reduce 16 lanes -> cross-wave via LDS ----
  #pragma unroll
  for (int mt = 0; mt < 4; mt++) {
    float pv[4] = {0.0f, 0.0f, 0.0f, 0.0f};
    #pragma unroll
    for (int nt = 0; nt < 4; nt++) {
      int col = 64*wave + 16*nt + l15;
      float bb = bback[col];
      float wv = Wv[col];
      #pragma unroll
      for (int r = 0; r < 4; r++)
        pv[r] += fmaxf(acc2[mt][nt][r] + bb, 0.0f) * wv;
    }
    #pragma unroll
    for (int r = 0; r < 4; r++) {
      float v = pv[r];
      v += __shfl_xor(v, 1, 64);
      v += __shfl_xor(v, 2, 64);
      v += __shfl_xor(v, 4, 64);
      v += __shfl_xor(v, 8, 64);
      if (l15 == 0) vpw[wave][16*mt + 4*quad + r] = v;  // each row written once per wave
    }
  }
  __syncthreads();

  // ---- phase 6: segment scatter (split arrays to spread atomic contention) ----
  if (tid < valid) {
    int g = (isA ? r0 : (nA + r0)) + tid;
    int seg = bidx[g];
    int split = blockIdx.x & (NSPLIT - 1);
    float vv = vpw[0][tid] + vpw[1][tid] + vpw[2][tid] + vpw[3][tid];
    atomicAdd(&vpart[split*NSEG + seg], vv);
    atomicAdd(&cpart[split*NSEG + seg], 1.0f);
  }
}

__global__ void final_kernel(const float* __restrict__ vpart, const float* __restrict__ cpart,
                             const float* __restrict__ bv, float* __restrict__ out, int nseg) {
  int s = blockIdx.x * blockDim.x + threadIdx.x;
  if (s < nseg) {
    float a = 0.0f, c = 0.0f;
    #pragma unroll 8
    for (int i = 0; i < NSPLIT; i++) { a += vpart[i*NSEG + s]; c += cpart[i*NSEG + s]; }
    out[s] = a / fmaxf(c, 1.0f) + bv[0];
  }
}

extern "C" void kernel_launch(void* const* d_in, const int* in_sizes, int n_in,
                              void* d_out, int out_size, void* d_ws, size_t ws_size,
                              hipStream_t stream) {
  const float* featsA = (const float*)d_in[0];
  const float* featsB = (const float*)d_in[1];
  const float* mA     = (const float*)d_in[2];
  const float* sA     = (const float*)d_in[3];
  const float* mB     = (const float*)d_in[4];
  const float* sB     = (const float*)d_in[5];
  const float* WA     = (const float*)d_in[6];
  const float* bA     = (const float*)d_in[7];
  const float* gA     = (const float*)d_in[8];
  const float* betaA  = (const float*)d_in[9];
  const float* WB     = (const float*)d_in[10];
  const float* bB     = (const float*)d_in[11];
  const float* gB     = (const float*)d_in[12];
  const float* betaB  = (const float*)d_in[13];
  const float* Wback  = (const float*)d_in[14];
  const float* bback  = (const float*)d_in[15];
  const float* Wv     = (const float*)d_in[16];
  const float* bv     = (const float*)d_in[17];
  const int*   bidx   = (const int*)d_in[18];

  const int nA = in_sizes[0] / 32;
  const int nB = in_sizes[1] / 48;
  char* ws = (char*)d_ws;
  float* vpart = (float*)(ws + WS_VPART);
  float* cpart = (float*)(ws + WS_CPART);
  float* out = (float*)d_out;

  prep_kernel<<<256, 256, 0, stream>>>(WA, WB, Wback, ws);

  const int tilesA = (nA + 63) / 64;
  const int tilesB = (nB + 63) / 64;
  fused_kernel<<<tilesA + tilesB, 256, 0, stream>>>(
      featsA, featsB, mA, sA, mB, sB, bA, gA, betaA, bB, gB, betaB,
      bback, Wv, bidx, ws, vpart, cpart, tilesA, nA, nB);

  final_kernel<<<(out_size + 255) / 256, 256, 0, stream>>>(vpart, cpart, bv, out, out_size);
}

// Round 2
// 400.545 us; speedup vs baseline: 3.0077x; 3.0077x over previous
//
#include <hip/hip_runtime.h>

#define NSEG 512
#define NSPLIT 32

typedef __attribute__((ext_vector_type(8))) short short8;
typedef __attribute__((ext_vector_type(4))) float floatx4;

// ws layout (bytes), all 16B-aligned
#define WS_WAT   0        // short [256][32]   WA^T
#define WS_WBT2  16384    // short [256][64]   WB^T (K padded 48->64 w/ zeros)
#define WS_W2GA  49152    // short [256][256]  (gA*Wback)^T
#define WS_W2GB  180224   // short [256][256]  (gB*Wback)^T
#define WS_C1A   311296   // float[256] gA . Wback[:,n]
#define WS_C2A   312320   // float[256] betaA . Wback[:,n] + bback
#define WS_C1B   313344
#define WS_C2B   314368
#define WS_INVA  315392   // float[32]  1/stdA
#define WS_INVB  315520   // float[48]  1/stdB
#define WS_VPART 315712   // float [NSPLIT][NSEG]
#define WS_CPART 381248   // float [NSPLIT][NSEG]
// end 446784

__device__ __forceinline__ short f2bf(float f) {  // RNE
  unsigned u = __builtin_bit_cast(unsigned, f);
  u += 0x7FFFu + ((u >> 16) & 1u);
  return (short)(u >> 16);
}

__global__ void prep_kernel(const float* __restrict__ WA, const float* __restrict__ WB,
                            const float* __restrict__ Wback,
                            const float* __restrict__ gA, const float* __restrict__ betaA,
                            const float* __restrict__ gB, const float* __restrict__ betaB,
                            const float* __restrict__ bback,
                            const float* __restrict__ sA, const float* __restrict__ sB,
                            char* __restrict__ ws) {
  short* waT  = (short*)(ws + WS_WAT);
  short* wbT2 = (short*)(ws + WS_WBT2);
  short* w2gA = (short*)(ws + WS_W2GA);
  short* w2gB = (short*)(ws + WS_W2GB);
  float* c1A = (float*)(ws + WS_C1A);
  float* c2A = (float*)(ws + WS_C2A);
  float* c1B = (float*)(ws + WS_C1B);
  float* c2B = (float*)(ws + WS_C2B);
  float* invA = (float*)(ws + WS_INVA);
  float* invB = (float*)(ws + WS_INVB);
  float* vz   = (float*)(ws + WS_VPART);
  int tid = blockIdx.x * blockDim.x + threadIdx.x;
  int stride = gridDim.x * blockDim.x;
  for (int i = tid; i < 32*256; i += stride) {          // WA[k][n] -> waT[n][k]
    int k = i >> 8, n = i & 255;
    waT[n*32 + k] = f2bf(WA[i]);
  }
  for (int i = tid; i < 256*64; i += stride) {          // WB[k][n] -> wbT2[n][k], pad K
    int n = i >> 6, k = i & 63;
    wbT2[i] = (k < 48) ? f2bf(WB[k*256 + n]) : (short)0;
  }
  for (int i = tid; i < 256*256; i += stride) {         // (g*Wback)[k][n] -> [n][k]
    int k = i >> 8, n = i & 255;
    float w = Wback[i];
    w2gA[n*256 + k] = f2bf(gA[k] * w);
    w2gB[n*256 + k] = f2bf(gB[k] * w);
  }
  if (blockIdx.x == 0 && threadIdx.x < 256) {
    int n = threadIdx.x;
    float a1 = 0.f, a2 = 0.f, b1 = 0.f, b2 = 0.f;
    for (int k = 0; k < 256; k++) {
      float w = Wback[k*256 + n];
      a1 += gA[k] * w;  a2 += betaA[k] * w;
      b1 += gB[k] * w;  b2 += betaB[k] * w;
    }
    c1A[n] = a1; c2A[n] = a2 + bback[n];
    c1B[n] = b1; c2B[n] = b2 + bback[n];
  }
  if (tid < 32) invA[tid] = 1.0f / sA[tid];
  if (tid < 48) invB[tid] = 1.0f / sB[tid];
  for (int i = tid; i < 2*NSPLIT*NSEG; i += stride) vz[i] = 0.0f;  // vpart+cpart
}

__global__ __launch_bounds__(256, 2) void fused_kernel(
    const float* __restrict__ featsA, const float* __restrict__ featsB,
    const float* __restrict__ mA, const float* __restrict__ mB,
    const float* __restrict__ bA, const float* __restrict__ bB,
    const float* __restrict__ Wv, const int* __restrict__ bidx,
    const char* __restrict__ ws, float* __restrict__ vpart, float* __restrict__ cpart,
    int tilesA, int nA, int nB)
{
  __shared__ __attribute__((aligned(16))) short ztile[64*264];   // h, bf16, stride 264
  __shared__ __attribute__((aligned(16))) float sred[64][4];
  __shared__ __attribute__((aligned(16))) float s2red[64][4];
  __shared__ __attribute__((aligned(16))) float vpw[64][4];

  const int tid  = threadIdx.x;
  const int wave = tid >> 6;
  const int lane = tid & 63;
  const int l15  = lane & 15;
  const int quad = lane >> 4;

  const bool isA = (blockIdx.x < (unsigned)tilesA);
  const int  tb  = isA ? blockIdx.x : (blockIdx.x - tilesA);
  const int  r0  = tb * 64;
  const int  nrows = isA ? nA : nB;
  const int  valid = min(64, nrows - r0);
  const float* feats = isA ? featsA : featsB;
  const float* meanp = isA ? mA : mB;
  const float* invp  = (const float*)(ws + (isA ? WS_INVA : WS_INVB));
  const float* biasp = isA ? bA : bB;
  const short* weT   = (const short*)(ws + (isA ? WS_WAT : WS_WBT2));
  const short* w2gT  = (const short*)(ws + (isA ? WS_W2GA : WS_W2GB));
  const float* c1p   = (const float*)(ws + (isA ? WS_C1A : WS_C1B));
  const float* c2p   = (const float*)(ws + (isA ? WS_C2A : WS_C2B));
  const int f       = isA ? 32 : 48;
  const int kstride = isA ? 32 : 64;
  const int ksteps  = isA ? 1 : 2;

  // per-lane column constants (cols 64*wave + 16*nt + l15)
  float b1v[4], c1v[4], c2v[4], wvv[4];
  #pragma unroll
  for (int nt = 0; nt < 4; nt++) {
    int col = 64*wave + 16*nt + l15;
    b1v[nt] = biasp[col];
    c1v[nt] = c1p[col];
    c2v[nt] = c2p[col];
    wvv[nt] = Wv[col];
  }

  // ---- GEMM1: h = relu(norm(feats) @ W1 + b1), A-frags straight from global ----
  floatx4 acc1[4][4];
  #pragma unroll
  for (int mt = 0; mt < 4; mt++)
    #pragma unroll
    for (int nt = 0; nt < 4; nt++)
      acc1[mt][nt] = 0.0f;

  for (int kk = 0; kk < ksteps; kk++) {
    const int k0 = kk*32 + quad*8;
    const bool kvalid = (k0 < f);
    floatx4 mv0 = {0,0,0,0}, mv1 = {0,0,0,0}, iv0 = {1,1,1,1}, iv1 = {1,1,1,1};
    if (kvalid) {
      mv0 = *(const floatx4*)(meanp + k0);  mv1 = *(const floatx4*)(meanp + k0 + 4);
      iv0 = *(const floatx4*)(invp + k0);   iv1 = *(const floatx4*)(invp + k0 + 4);
    }
    short8 af[4];
    #pragma unroll
    for (int mt = 0; mt < 4; mt++) {
      short8 a = {0,0,0,0,0,0,0,0};
      int row = 16*mt + l15;
      if (kvalid && row < valid) {
        const float* fp = feats + (size_t)(r0 + row) * f + k0;
        floatx4 x0 = *(const floatx4*)fp;
        floatx4 x1 = *(const floatx4*)(fp + 4);
        #pragma unroll
        for (int e = 0; e < 4; e++) {
          float h0 = (x0[e] - mv0[e]) * iv0[e];
          h0 = fminf(fmaxf(h0, -5.0f), 5.0f);
          a[e] = f2bf(h0);
          float h1 = (x1[e] - mv1[e]) * iv1[e];
          h1 = fminf(fmaxf(h1, -5.0f), 5.0f);
          a[4+e] = f2bf(h1);
        }
      }
      af[mt] = a;
    }
    short8 bfw[4];
    #pragma unroll
    for (int nt = 0; nt < 4; nt++)
      bfw[nt] = *(const short8*)(weT + (size_t)(64*wave + 16*nt + l15) * kstride + kk*32 + quad*8);
    #pragma unroll
    for (int mt = 0; mt < 4; mt++)
      #pragma unroll
      for (int nt = 0; nt < 4; nt++)
        acc1[mt][nt] = __builtin_amdgcn_mfma_f32_16x16x32_bf16(af[mt], bfw[nt], acc1[mt][nt], 0, 0, 0);
  }

  // ---- epilogue1: h=relu(.+b1) -> ztile (bf16) + stats (s, s2) from registers ----
  float sacc[4][4], s2acc[4][4];
  #pragma unroll
  for (int mt = 0; mt < 4; mt++)
    #pragma unroll
    for (int r = 0; r < 4; r++) { sacc[mt][r] = 0.f; s2acc[mt][r] = 0.f; }

  #pragma unroll
  for (int nt = 0; nt < 4; nt++) {
    int col = 64*wave + 16*nt + l15;
    #pragma unroll
    for (int mt = 0; mt < 4; mt++)
      #pragma unroll
      for (int r = 0; r < 4; r++) {
        float h = fmaxf(acc1[mt][nt][r] + b1v[nt], 0.0f);
        sacc[mt][r] += h;
        s2acc[mt][r] = fmaf(h, h, s2acc[mt][r]);
        ztile[(16*mt + 4*quad + r)*264 + col] = f2bf(h);
      }
  }
  // reduce stats over the 16 l15 lanes; C-layout rows == epilogue2 rows, no redistribution
  #pragma unroll
  for (int mt = 0; mt < 4; mt++)
    #pragma unroll
    for (int r = 0; r < 4; r++) {
      float s = sacc[mt][r], s2 = s2acc[mt][r];
      s  += __shfl_xor(s, 1, 64);  s2 += __shfl_xor(s2, 1, 64);
      s  += __shfl_xor(s, 2, 64);  s2 += __shfl_xor(s2, 2, 64);
      s  += __shfl_xor(s, 4, 64);  s2 += __shfl_xor(s2, 4, 64);
      s  += __shfl_xor(s, 8, 64);  s2 += __shfl_xor(s2, 8, 64);
      if (l15 == 0) {
        int row = 16*mt + 4*quad + r;
        sred[row][wave] = s;
        s2red[row][wave] = s2;
      }
    }
  __syncthreads();

  // ---- per-row LN scalars for MY epilogue2 rows ----
  float rsv[4][4], mrsv[4][4];
  #pragma unroll
  for (int mt = 0; mt < 4; mt++)
    #pragma unroll
    for (int r = 0; r < 4; r++) {
      int row = 16*mt + 4*quad + r;
      floatx4 sv  = *(const floatx4*)sred[row];
      floatx4 s2v = *(const floatx4*)s2red[row];
      float s  = sv[0] + sv[1] + sv[2] + sv[3];
      float s2 = s2v[0] + s2v[1] + s2v[2] + s2v[3];
      float mu  = s * (1.0f/256.0f);
      float var = fmaxf(s2 * (1.0f/256.0f) - mu*mu, 0.0f);
      float rs  = rsqrtf(var + 1e-5f);
      rsv[mt][r]  = rs;
      mrsv[mt][r] = mu * rs;
    }

  // ---- GEMM2: q = h @ (g*Wback), K=256 ----
  floatx4 acc2[4][4];
  #pragma unroll
  for (int mt = 0; mt < 4; mt++)
    #pragma unroll
    for (int nt = 0; nt < 4; nt++)
      acc2[mt][nt] = 0.0f;

  #pragma unroll
  for (int kk = 0; kk < 8; kk++) {
    short8 bf[4];
    #pragma unroll
    for (int nt = 0; nt < 4; nt++)
      bf[nt] = *(const short8*)(w2gT + (size_t)(64*wave + 16*nt + l15)*256 + kk*32 + quad*8);
    short8 af[4];
    #pragma unroll
    for (int mt = 0; mt < 4; mt++)
      af[mt] = *(const short8*)(ztile + (16*mt + l15)*264 + kk*32 + quad*8);
    #pragma unroll
    for (int mt = 0; mt < 4; mt++)
      #pragma unroll
      for (int nt = 0; nt < 4; nt++)
        acc2[mt][nt] = __builtin_amdgcn_mfma_f32_16x16x32_bf16(af[mt], bf[nt], acc2[mt][nt], 0, 0, 0);
  }

  // ---- epilogue2: y = relu(rs*q - mu*rs*c1 + c2); v = y . Wv ----
  #pragma unroll
  for (int mt = 0; mt < 4; mt++)
    #pragma unroll
    for (int r = 0; r < 4; r++) {
      float rs = rsv[mt][r], mrs = mrsv[mt][r];
      float pv = 0.0f;
      #pragma unroll
      for (int nt = 0; nt < 4; nt++) {
        float t = fmaf(-mrs, c1v[nt], c2v[nt]);
        float y = fmaf(rs, acc2[mt][nt][r], t);
        y = fmaxf(y, 0.0f);
        pv = fmaf(y, wvv[nt], pv);
      }
      pv += __shfl_xor(pv, 1, 64);
      pv += __shfl_xor(pv, 2, 64);
      pv += __shfl_xor(pv, 4, 64);
      pv += __shfl_xor(pv, 8, 64);
      if (l15 == 0) vpw[16*mt + 4*quad + r][wave] = pv;
    }
  __syncthreads();

  // ---- scatter ----
  if (tid < valid) {
    floatx4 vv = *(const floatx4*)vpw[tid];
    float v = vv[0] + vv[1] + vv[2] + vv[3];
    int g = (isA ? r0 : (nA + r0)) + tid;
    int seg = bidx[g];
    int split = blockIdx.x & (NSPLIT - 1);
    atomicAdd(&vpart[split*NSEG + seg], v);
    atomicAdd(&cpart[split*NSEG + seg], 1.0f);
  }
}

__global__ void final_kernel(const float* __restrict__ vpart, const float* __restrict__ cpart,
                             const float* __restrict__ bv, float* __restrict__ out, int nseg) {
  int s = blockIdx.x * blockDim.x + threadIdx.x;
  if (s < nseg) {
    float a = 0.0f, c = 0.0f;
    #pragma unroll 8
    for (int i = 0; i < NSPLIT; i++) { a += vpart[i*NSEG + s]; c += cpart[i*NSEG + s]; }
    out[s] = a / fmaxf(c, 1.0f) + bv[0];
  }
}

extern "C" void kernel_launch(void* const* d_in, const int* in_sizes, int n_in,
                              void* d_out, int out_size, void* d_ws, size_t ws_size,
                              hipStream_t stream) {
  const float* featsA = (const float*)d_in[0];
  const float* featsB = (const float*)d_in[1];
  const float* mA     = (const float*)d_in[2];
  const float* sA     = (const float*)d_in[3];
  const float* mB     = (const float*)d_in[4];
  const float* sB     = (const float*)d_in[5];
  const float* WA     = (const float*)d_in[6];
  const float* bA     = (const float*)d_in[7];
  const float* gA     = (const float*)d_in[8];
  const float* betaA  = (const float*)d_in[9];
  const float* WB     = (const float*)d_in[10];
  const float* bB     = (const float*)d_in[11];
  const float* gB     = (const float*)d_in[12];
  const float* betaB  = (const float*)d_in[13];
  const float* Wback  = (const float*)d_in[14];
  const float* bback  = (const float*)d_in[15];
  const float* Wv     = (const float*)d_in[16];
  const float* bv     = (const float*)d_in[17];
  const int*   bidx   = (const int*)d_in[18];

  const int nA = in_sizes[0] / 32;
  const int nB = in_sizes[1] / 48;
  char* ws = (char*)d_ws;
  float* vpart = (float*)(ws + WS_VPART);
  float* cpart = (float*)(ws + WS_CPART);
  float* out = (float*)d_out;

  prep_kernel<<<256, 256, 0, stream>>>(WA, WB, Wback, gA, betaA, gB, betaB,
                                       bback, sA, sB, ws);

  const int tilesA = (nA + 63) / 64;
  const int tilesB = (nB + 63) / 64;
  fused_kernel<<<tilesA + tilesB, 256, 0, stream>>>(
      featsA, featsB, mA, mB, bA, bB, Wv, bidx, ws, vpart, cpart, tilesA, nA, nB);

  final_kernel<<<(out_size + 255) / 256, 256, 0, stream>>>(vpart, cpart, bv, out, out_size);
}